// Round 11
// baseline (258.009 us; speedup 1.0000x reference)
//
#include <hip/hip_runtime.h>
#include <hip/hip_bf16.h>

typedef __attribute__((ext_vector_type(8))) short short8;
typedef __attribute__((ext_vector_type(4))) float f32x4;
typedef __attribute__((ext_vector_type(4))) unsigned short u16x4;

#define MFMA16(a,b,c) __builtin_amdgcn_mfma_f32_16x16x32_bf16((a),(b),(c),0,0,0)

__device__ __forceinline__ ushort f2bf(float x) {
  union { float f; unsigned u; } v; v.f = x;
  unsigned u = v.u;
  u = (u + 0x7fffu + ((u >> 16) & 1u)) >> 16;
  return (ushort)u;
}

__device__ __forceinline__ float bf2f(ushort u) {
  union { unsigned u; float f; } v; v.u = ((unsigned)u) << 16;
  return v.f;
}

__device__ __forceinline__ short8 ld8(const ushort* p) {
  return *reinterpret_cast<const short8*>(p);
}

__device__ __forceinline__ f32x4 ld4(const float* p) {
  return *reinterpret_cast<const f32x4*>(p);
}

// ---- kernel 0: fp32 -> bf16 conversion (vectorized float4 -> ushort4) ----
__global__ void conv_kernel(const float* __restrict__ value,
                            const float* __restrict__ w_in,
                            const float* __restrict__ w_out,
                            ushort* __restrict__ vbf,
                            ushort* __restrict__ wbf,
                            ushort* __restrict__ owbf) {
  int i = blockIdx.x * 256 + threadIdx.x;   // float4 index
  const float* src; ushort* dst; int j;
  if (i < 524288)      { src = value; dst = vbf;  j = i; }
  else if (i < 573440) { src = w_in;  dst = wbf;  j = i - 524288; }
  else                 { src = w_out; dst = owbf; j = i - 573440; }
  float4 v = reinterpret_cast<const float4*>(src)[j];
  u16x4 o;
  o[0] = f2bf(v.x); o[1] = f2bf(v.y); o[2] = f2bf(v.z); o[3] = f2bf(v.w);
  reinterpret_cast<u16x4*>(dst)[j] = o;
}

// ---- kernel 1: qkv projection GEMM (8192x256)@(256x768)^T, scatter to head layouts ----
__global__ __launch_bounds__(256) void qkv_kernel(
    const ushort* __restrict__ vbf, const ushort* __restrict__ wbf,
    const float* __restrict__ bias,
    ushort* __restrict__ qh, ushort* __restrict__ kh, ushort* __restrict__ vv) {
  int tid = threadIdx.x;
  int wave = tid >> 6, lane = tid & 63;
  int lq = lane & 15, lg = lane >> 4;
  int r0 = blockIdx.x * 16;
  int c0 = (blockIdx.y * 4 + wave) * 16;
  f32x4 acc = {0.f, 0.f, 0.f, 0.f};
  const ushort* ap = vbf + (size_t)(r0 + lq) * 256 + lg * 8;
  const ushort* bp = wbf + (size_t)(c0 + lq) * 256 + lg * 8;
#pragma unroll
  for (int k0 = 0; k0 < 256; k0 += 32)
    acc = MFMA16(ld8(ap + k0), ld8(bp + k0), acc);
  int c = c0 + lq;
  float bv = bias[c];
#pragma unroll
  for (int r = 0; r < 4; ++r) {
    int row = r0 + lg * 4 + r;       // row = n*8 + b
    int n = row >> 3, b = row & 7;
    float v = acc[r] + bv;
    if (c < 256) {
      int h = c >> 5, d = c & 31;
      qh[((size_t)(b * 8 + h) * 1024 + n) * 32 + d] = f2bf(v * 0.17677669529663689f);
    } else if (c < 512) {
      int cc = c - 256, h = cc >> 5, d = cc & 31;
      kh[((size_t)(b * 8 + h) * 1024 + n) * 32 + d] = f2bf(v);
    } else {
      int cc = c - 512, h = cc >> 5, d = cc & 31;
      vv[((size_t)(b * 8 + h) * 1024 + n) * 32 + d] = f2bf(v);
    }
  }
}

// ---- kernel 1b: transpose vv[bh][m][d] -> vt[bh][d][m], coalesced both sides ----
__global__ __launch_bounds__(256) void vtrans_kernel(const ushort* __restrict__ vv,
                                                     ushort* __restrict__ vt) {
  __shared__ ushort t[32][73];
  int tid = threadIdx.x;
  int bh = blockIdx.y, m0 = blockIdx.x * 64;
  int mm = tid >> 2, d0 = (tid & 3) * 8;
  short8 v = ld8(vv + ((size_t)bh * 1024 + m0 + mm) * 32 + d0);
#pragma unroll
  for (int j = 0; j < 8; ++j) t[d0 + j][mm] = (ushort)v[j];
  __syncthreads();
  int d = tid >> 3, mg = (tid & 7) * 8;
  short8 o;
#pragma unroll
  for (int j = 0; j < 8; ++j) o[j] = (short)t[d][mg + j];
  *reinterpret_cast<short8*>(vt + ((size_t)bh * 32 + d) * 1024 + m0 + mg) = o;
}

// ---- kernel 2a: score pass. grid (8, 64, 4) = 2048 blocks, NO barriers, no PV,
// no avg state -> ~55 VGPR -> deep TLP streaming of the pos tensor.
// Block (b, n0-chunk, m-quarter). Wave owns 64 m-cols, 2 u-steps of 32.
// Writes unnormalized bf16 w to wbuf[bh][n][m] and per-wave rowsum partials
// to rsum[bh][n][16] (slot mh*4+wave). Deterministic: every slot written once.
__global__ __launch_bounds__(256, 4) void score_kernel(
    const ushort* __restrict__ qh, const ushort* __restrict__ kh,
    const float* __restrict__ pos, ushort* __restrict__ wbuf,
    float* __restrict__ rsum) {
  int tid = threadIdx.x;
  int wave = tid >> 6, lane = tid & 63;
  int lq = lane & 15, lg = lane >> 4;
  int b = blockIdx.x;
  int n0 = blockIdx.y * 16;
  int mh = blockIdx.z;
  int ra = ((lq >> 2) << 3) + (lq & 3);   // permuted K-row offset
  int mw = mh * 256 + wave * 64;

  for (int h = 0; h < 8; ++h) {
    int bh = b * 8 + h;
    const ushort* kp = kh + (size_t)bh * 32768;
    const float* pp = pos + ((size_t)bh << 20) + (size_t)(n0 + lq) * 1024;
    ushort* wp = wbuf + ((size_t)bh << 20) + (size_t)(n0 + lq) * 1024;
    short8 qa = ld8(qh + ((size_t)bh * 1024 + n0 + lq) * 32 + lg * 8);
    float rs = 0.f;
#pragma unroll
    for (int u = 0; u < 2; ++u) {
      int mu = mw + u * 32;
      short8 ka = ld8(kp + (size_t)(mu + ra) * 32 + lg * 8);
      short8 kb = ld8(kp + (size_t)(mu + ra + 4) * 32 + lg * 8);
      f32x4 p0 = ld4(pp + mu + lg * 8);
      f32x4 p1 = ld4(pp + mu + lg * 8 + 4);
      f32x4 z = {0.f, 0.f, 0.f, 0.f};
      f32x4 SA = MFMA16(ka, qa, z);   // SA[i] = S[mu+lg*8+i][n=lq]
      f32x4 SB = MFMA16(kb, qa, z);   // SB[i] = S[mu+lg*8+4+i][n=lq]
      short8 w8;
#pragma unroll
      for (int i = 0; i < 4; ++i) {
        float p = fminf(10.f, fmaxf(-10.f, p0[i]));
        float c = fminf(10.f, fmaxf(-10.f, SA[i]));
        float w = __expf(c - 10.f) * __builtin_amdgcn_rcpf(1.f + __expf(-p));
        rs += w;
        w8[i] = (short)f2bf(w);
      }
#pragma unroll
      for (int i = 0; i < 4; ++i) {
        float p = fminf(10.f, fmaxf(-10.f, p1[i]));
        float c = fminf(10.f, fmaxf(-10.f, SB[i]));
        float w = __expf(c - 10.f) * __builtin_amdgcn_rcpf(1.f + __expf(-p));
        rs += w;
        w8[4 + i] = (short)f2bf(w);
      }
      *reinterpret_cast<short8*>(wp + mu + lg * 8) = w8;
    }
    // reduce rowsum over the 4 lg groups; lanes lq hold row n0+lq
    rs += __shfl_xor(rs, 16);
    rs += __shfl_xor(rs, 32);
    if (lane < 16)
      rsum[(((size_t)bh << 10) + n0 + lq) * 16 + mh * 4 + wave] = rs;
  }
}

// ---- kernel 2b: PV + avg + ao. grid (8, 64). Reads w back (L3-resident),
// V from L2, rowsums from rsum. Same fragment algebra as the verified R8 body.
__global__ __launch_bounds__(256, 3) void pv_kernel(
    const ushort* __restrict__ wbuf, const float* __restrict__ rsum,
    const ushort* __restrict__ vt, ushort* __restrict__ ao,
    float* __restrict__ avg_out) {
  __shared__ float pvred[2][4][16][32];   // double-buffered PV partials

  int tid = threadIdx.x;
  int wave = tid >> 6, lane = tid & 63;
  int lq = lane & 15, lg = lane >> 4;
  int b = blockIdx.x;
  int n0 = blockIdx.y * 16;

  float avg[8][8];
#pragma unroll
  for (int u = 0; u < 8; ++u)
#pragma unroll
    for (int i = 0; i < 8; ++i) avg[u][i] = 0.f;

  for (int h = 0; h < 8; ++h) {
    int bh = b * 8 + h;
    const ushort* vp = vt + (size_t)bh * 32768 + wave * 256 + lg * 8;
    const ushort* wp = wbuf + ((size_t)bh << 20) + (size_t)(n0 + lq) * 1024 + wave * 256 + lg * 8;
    // invr for this lane's row n = n0+lq (16 partials, final since pass A done)
    const float* rp = rsum + (((size_t)bh << 10) + n0 + lq) * 16;
    f32x4 s0 = ld4(rp), s1 = ld4(rp + 4), s2 = ld4(rp + 8), s3 = ld4(rp + 12);
    float invr = __builtin_amdgcn_rcpf(
        s0[0] + s0[1] + s0[2] + s0[3] + s1[0] + s1[1] + s1[2] + s1[3] +
        s2[0] + s2[1] + s2[2] + s2[3] + s3[0] + s3[1] + s3[2] + s3[3]);

    f32x4 acc0 = {0.f, 0.f, 0.f, 0.f}, acc1 = {0.f, 0.f, 0.f, 0.f};
#pragma unroll
    for (int u = 0; u < 8; ++u) {
      short8 w8 = ld8(wp + u * 32);
      short8 va = ld8(vp + (size_t)lq * 1024 + u * 32);
      short8 vb = ld8(vp + (size_t)(lq + 16) * 1024 + u * 32);
      acc0 = MFMA16(w8, va, acc0);          // O[n=lg*4+j][d=lq]
      acc1 = MFMA16(w8, vb, acc1);          // O[n=lg*4+j][d=lq+16]
#pragma unroll
      for (int i = 0; i < 8; ++i)
        avg[u][i] += bf2f((ushort)w8[i]) * invr;
    }
    int buf = h & 1;
#pragma unroll
    for (int j = 0; j < 4; ++j) {
      pvred[buf][wave][lg * 4 + j][lq] = acc0[j];
      pvred[buf][wave][lg * 4 + j][lq + 16] = acc1[j];
    }
    __syncthreads();                        // the only barrier per head
    {
      int n = tid >> 4, d = tid & 15;
      const float* rp2 = rsum + (((size_t)bh << 10) + n0 + n) * 16;
      f32x4 t0 = ld4(rp2), t1 = ld4(rp2 + 4), t2 = ld4(rp2 + 8), t3 = ld4(rp2 + 12);
      float invn = __builtin_amdgcn_rcpf(
          t0[0] + t0[1] + t0[2] + t0[3] + t1[0] + t1[1] + t1[2] + t1[3] +
          t2[0] + t2[1] + t2[2] + t2[3] + t3[0] + t3[1] + t3[2] + t3[3]);
      float v0 = pvred[buf][0][n][d] + pvred[buf][1][n][d] +
                 pvred[buf][2][n][d] + pvred[buf][3][n][d];
      float v1 = pvred[buf][0][n][d + 16] + pvred[buf][1][n][d + 16] +
                 pvred[buf][2][n][d + 16] + pvred[buf][3][n][d + 16];
      size_t base = ((size_t)(n0 + n) * 8 + b) * 256 + h * 32;
      ao[base + d] = f2bf(v0 * invn);
      ao[base + d + 16] = f2bf(v1 * invn);
    }
  }
  // ---- averaged attention (mean over heads): row n0+lq, cols wave*256+u*32+lg*8 ----
  float* op = avg_out + (size_t)b * 1048576 + (size_t)(n0 + lq) * 1024 + wave * 256;
#pragma unroll
  for (int u = 0; u < 8; ++u) {
    f32x4 v0 = {avg[u][0] * 0.125f, avg[u][1] * 0.125f, avg[u][2] * 0.125f, avg[u][3] * 0.125f};
    f32x4 v1 = {avg[u][4] * 0.125f, avg[u][5] * 0.125f, avg[u][6] * 0.125f, avg[u][7] * 0.125f};
    __builtin_nontemporal_store(v0, reinterpret_cast<f32x4*>(op + u * 32 + lg * 8));
    __builtin_nontemporal_store(v1, reinterpret_cast<f32x4*>(op + u * 32 + lg * 8 + 4));
  }
}

// ---- kernel 3: output projection (8192x256)@(256x256)^T + bias -> d_out (fp32) ----
__global__ __launch_bounds__(256) void oproj_kernel(
    const ushort* __restrict__ ao, const ushort* __restrict__ owbf,
    const float* __restrict__ ob, float* __restrict__ outp) {
  int tid = threadIdx.x;
  int wave = tid >> 6, lane = tid & 63;
  int lq = lane & 15, lg = lane >> 4;
  int r0 = blockIdx.x * 16;
  int c0 = (blockIdx.y * 4 + wave) * 16;
  f32x4 acc = {0.f, 0.f, 0.f, 0.f};
  const ushort* ap = ao + (size_t)(r0 + lq) * 256 + lg * 8;
  const ushort* bp = owbf + (size_t)(c0 + lq) * 256 + lg * 8;
#pragma unroll
  for (int k0 = 0; k0 < 256; k0 += 32)
    acc = MFMA16(ld8(ap + k0), ld8(bp + k0), acc);
  int c = c0 + lq;
  float bv = ob[c];
#pragma unroll
  for (int r = 0; r < 4; ++r) {
    int row = r0 + lg * 4 + r;
    outp[(size_t)row * 256 + c] = acc[r] + bv;
  }
}

extern "C" void kernel_launch(void* const* d_in, const int* in_sizes, int n_in,
                              void* d_out, int out_size, void* d_ws, size_t ws_size,
                              hipStream_t stream) {
  const float* value = (const float*)d_in[0];
  const float* pos   = (const float*)d_in[1];
  const float* w_in  = (const float*)d_in[2];
  const float* b_in  = (const float*)d_in[3];
  const float* w_out = (const float*)d_in[4];
  const float* b_out = (const float*)d_in[5];

  char* ws = (char*)d_ws;
  ushort* vbf  = (ushort*)(ws);                 // 8192x256 bf16 (4 MB); reused as vt after qkv
  ushort* wbf  = (ushort*)(ws + 4194304);       // 768x256 bf16
  ushort* owbf = (ushort*)(ws + 4587520);       // 256x256 bf16
  ushort* qh   = (ushort*)(ws + 4718592);       // 64x1024x32 bf16 (4 MB)
  ushort* kh   = (ushort*)(ws + 8912896);       // 64x1024x32 bf16 (4 MB)
  ushort* vv   = (ushort*)(ws + 13107200);      // 64x1024x32 bf16 (4 MB, row-major V)
  ushort* vt   = (ushort*)(ws);                 // 64x32x1024 bf16 (4 MB, overlays dead vbf)
  ushort* ao   = (ushort*)(ws + 17301504);      // 8192x256 bf16 (4 MB)
  ushort* wbuf = (ushort*)(ws + 33554432);      // 64x1024x1024 bf16 (128 MB) unnormalized w
  float*  rsum = (float*)(ws + 167772160);      // 64x1024x16 fp32 (4 MB) rowsum partials

  float* outp = (float*)d_out;                  // (N,B,E) fp32
  float* avgp = outp + 2097152;                 // (B,N,N) fp32

  conv_kernel<<<2304, 256, 0, stream>>>(value, w_in, w_out, vbf, wbf, owbf);
  qkv_kernel<<<dim3(512, 12), 256, 0, stream>>>(vbf, wbf, b_in, qh, kh, vv);
  vtrans_kernel<<<dim3(16, 64), 256, 0, stream>>>(vv, vt);
  score_kernel<<<dim3(8, 64, 4), 256, 0, stream>>>(qh, kh, pos, wbuf, rsum);
  pv_kernel<<<dim3(8, 64), 256, 0, stream>>>(wbuf, rsum, vt, ao, avgp);
  oproj_kernel<<<dim3(512, 4), 256, 0, stream>>>(ao, owbf, b_out, outp);
}